// Round 1
// baseline (297.333 us; speedup 1.0000x reference)
//
#include <hip/hip_runtime.h>

#define S 256
#define D 256
#define DFF 1024
#define NB 2          // batch
#define R_TOT 512     // NB*S rows
#define RES 1.0f
#define ALT 1.0f      // 2.0 - RES

// ---------- block-wide helpers (blockDim.x == 256) ----------
__device__ __forceinline__ float block_sum(float v, float* red) {
    int t = threadIdx.x;
    red[t] = v; __syncthreads();
    for (int off = 128; off; off >>= 1) {
        if (t < off) red[t] += red[t + off];
        __syncthreads();
    }
    float r = red[0]; __syncthreads();
    return r;
}
__device__ __forceinline__ float block_max(float v, float* red) {
    int t = threadIdx.x;
    red[t] = v; __syncthreads();
    for (int off = 128; off; off >>= 1) {
        if (t < off) red[t] = fmaxf(red[t], red[t + off]);
        __syncthreads();
    }
    float r = red[0]; __syncthreads();
    return r;
}

// ---------- K1: embedding + positional encoding ----------
// grid 512 (one row), block 256 (one col each)
__global__ __launch_bounds__(256) void k_embed(
    const int* __restrict__ x, const float* __restrict__ mask,
    const int* __restrict__ use_pos, const float* __restrict__ pos_enc,
    const float* __restrict__ emb_W, const float* __restrict__ emb_b,
    float* __restrict__ h)
{
    __shared__ float red[256];
    int r = blockIdx.x, d = threadIdx.x;
    int b = r >> 8, s = r & 255;
    // idx = cumsum(1 - mask)[s]  (inclusive)
    float mv = (d <= s) ? (1.0f - mask[b * S + d]) : 0.0f;
    float cum = block_sum(mv, red);
    int idx = (int)(cum + 0.5f);
    int xv = x[r];
    float acc = emb_b[d];
#pragma unroll
    for (int k = 0; k < 16; k++)
        if ((xv >> k) & 1) acc += emb_W[k * D + d];
    acc *= 16.0f;                       // sqrt(d_model)
    if (use_pos[0]) acc += pos_enc[idx * D + d];
    h[r * D + d] = acc;
}

// ---------- K2: fused qkv = h@wW+wb ; qa' = qkv@W1a + b1 ; qb = qkv@W1b ----------
// grid 128 (4 rows each), block 512
__global__ __launch_bounds__(512) void k_qkv(
    const float* __restrict__ h, const float* __restrict__ wW, const float* __restrict__ wb,
    const float* __restrict__ nnW1, const float* __restrict__ nnb1,
    float* __restrict__ qkv, float* __restrict__ qa, float* __restrict__ qb)
{
    __shared__ float As[4][256];
    __shared__ float Qs[4][256];
    int r0 = blockIdx.x * 4;
    int c = threadIdx.x & 255;
    int half = threadIdx.x >> 8;     // rows {0,1} or {2,3}
    for (int idx = threadIdx.x; idx < 4 * 256; idx += 512)
        As[idx >> 8][idx & 255] = h[(r0 + (idx >> 8)) * D + (idx & 255)];
    __syncthreads();
    int i0 = half * 2;
    float acc0 = wb[c], acc1 = wb[c];
    for (int k = 0; k < D; k++) {
        float w = wW[k * D + c];
        acc0 = fmaf(As[i0][k], w, acc0);
        acc1 = fmaf(As[i0 + 1][k], w, acc1);
    }
    qkv[(r0 + i0) * D + c] = acc0;     Qs[i0][c] = acc0;
    qkv[(r0 + i0 + 1) * D + c] = acc1; Qs[i0 + 1][c] = acc1;
    __syncthreads();
    float a0 = nnb1[c], a1 = nnb1[c], b0 = 0.f, b1v = 0.f;
    for (int k = 0; k < D; k++) {
        float wa = nnW1[k * D + c];
        float wbv = nnW1[(k + D) * D + c];
        float q0 = Qs[i0][k], q1 = Qs[i0 + 1][k];
        a0 = fmaf(q0, wa, a0);  a1 = fmaf(q1, wa, a1);
        b0 = fmaf(q0, wbv, b0); b1v = fmaf(q1, wbv, b1v);
    }
    qa[(r0 + i0) * D + c] = a0;     qa[(r0 + i0 + 1) * D + c] = a1;
    qb[(r0 + i0) * D + c] = b0;     qb[(r0 + i0 + 1) * D + c] = b1v;
}

// ---------- K3: g[b,i,j] = sum_h relu(qa'[i,h]+qb[j,h]) * w2[h] ----------
// grid 128 (= NB * S/4), block 512 (256 j-cols x 2 h-halves)
__global__ __launch_bounds__(512) void k_g(
    const float* __restrict__ qa, const float* __restrict__ qb,
    const float* __restrict__ w2, float* __restrict__ g)
{
    __shared__ float qa_s[4][256];
    __shared__ float w2_s[256];
    __shared__ float tmp[4][256];
    int b = blockIdx.x >> 6;
    int i0 = (blockIdx.x & 63) * 4;
    int j = threadIdx.x & 255;
    int half = threadIdx.x >> 8;
    for (int idx = threadIdx.x; idx < 4 * 256; idx += 512)
        qa_s[idx >> 8][idx & 255] = qa[(b * S + i0 + (idx >> 8)) * D + (idx & 255)];
    if (threadIdx.x < 256) w2_s[threadIdx.x] = w2[threadIdx.x];
    __syncthreads();
    float acc0 = 0, acc1 = 0, acc2 = 0, acc3 = 0;
    const float* qbr = qb + (b * S + j) * D + half * 128;
    const int hb = half * 128;
    for (int hh = 0; hh < 128; hh++) {
        float qv = qbr[hh];
        float wv = w2_s[hb + hh];
        float v;
        v = qa_s[0][hb + hh] + qv; acc0 = fmaf(fmaxf(v, 0.f), wv, acc0);
        v = qa_s[1][hb + hh] + qv; acc1 = fmaf(fmaxf(v, 0.f), wv, acc1);
        v = qa_s[2][hb + hh] + qv; acc2 = fmaf(fmaxf(v, 0.f), wv, acc2);
        v = qa_s[3][hb + hh] + qv; acc3 = fmaf(fmaxf(v, 0.f), wv, acc3);
    }
    if (half) { tmp[0][j] = acc0; tmp[1][j] = acc1; tmp[2][j] = acc2; tmp[3][j] = acc3; }
    __syncthreads();
    if (!half) {
        g[(b * S + i0 + 0) * S + j] = acc0 + tmp[0][j];
        g[(b * S + i0 + 1) * S + j] = acc1 + tmp[1][j];
        g[(b * S + i0 + 2) * S + j] = acc2 + tmp[2][j];
        g[(b * S + i0 + 3) * S + j] = acc3 + tmp[3][j];
    }
}

// ---------- K4: sim = g + g^T + 2*b2 + mask*-1e9 ; softmax ; ao = attn @ qkv ----------
// grid 256 (2 rows each), block 256
__global__ __launch_bounds__(256) void k_attn(
    const float* __restrict__ g, const float* __restrict__ mask,
    const float* __restrict__ b2p, const float* __restrict__ qkv,
    float* __restrict__ ao)
{
    __shared__ float attn_s[256];
    __shared__ float red[256];
    int r0 = blockIdx.x * 2;
    int b = r0 >> 8;
    int t = threadIdx.x;
    float two_b2 = 2.0f * b2p[0];
    float mbias = mask[b * S + t] * (-1e9f);
    for (int row = 0; row < 2; row++) {
        int i = (r0 & 255) + row;
        float sv = g[(b * S + i) * S + t] + g[(b * S + t) * S + i] + two_b2 + mbias;
        float m = block_max(sv, red);
        float e = __expf(sv - m);
        float inv = 1.0f / block_sum(e, red);
        attn_s[t] = e * inv;
        __syncthreads();
        float acc = 0.f;
        const float* qkvb = qkv + (size_t)b * S * D + t;
        for (int jj = 0; jj < S; jj++) acc = fmaf(attn_s[jj], qkvb[jj * D], acc);
        ao[(b * S + i) * D + t] = acc;
        __syncthreads();
    }
}

// ---------- K5: o1 = LN1(RES*h + ALT*(ao@outW + outb)) ----------
// grid 256 (2 rows), block 256
__global__ __launch_bounds__(256) void k_proj_ln(
    const float* __restrict__ ao, const float* __restrict__ outW, const float* __restrict__ outb,
    const float* __restrict__ h, const float* __restrict__ lng, const float* __restrict__ lnb,
    float* __restrict__ o1)
{
    __shared__ float as[2][256];
    __shared__ float red[256];
    int r0 = blockIdx.x * 2;
    int c = threadIdx.x;
    as[0][c] = ao[r0 * D + c];
    as[1][c] = ao[(r0 + 1) * D + c];
    __syncthreads();
    float acc0 = outb[c], acc1 = outb[c];
    for (int k = 0; k < D; k++) {
        float w = outW[k * D + c];
        acc0 = fmaf(as[0][k], w, acc0);
        acc1 = fmaf(as[1][k], w, acc1);
    }
    float gg = lng[c], bb = lnb[c];
#pragma unroll
    for (int row = 0; row < 2; row++) {
        float acc = row ? acc1 : acc0;
        float v = RES * h[(r0 + row) * D + c] + ALT * acc;
        float mu = block_sum(v, red) * (1.0f / 256.0f);
        float dv = v - mu;
        float var = block_sum(dv * dv, red) * (1.0f / 256.0f);
        o1[(r0 + row) * D + c] = dv * rsqrtf(var + 1e-6f) * gg + bb;
    }
}

// ---------- K6: f1 = relu(o1 @ ffnW1 + ffnb1) ----------
// grid (128, 4): 4 rows x 256-col block; block 256
__global__ __launch_bounds__(256) void k_ffn1(
    const float* __restrict__ o1, const float* __restrict__ W1, const float* __restrict__ b1,
    float* __restrict__ f1)
{
    __shared__ float as[4][256];
    int r0 = blockIdx.x * 4;
    int c = blockIdx.y * 256 + threadIdx.x;
    for (int idx = threadIdx.x; idx < 4 * 256; idx += 256)
        as[idx >> 8][idx & 255] = o1[(r0 + (idx >> 8)) * D + (idx & 255)];
    __syncthreads();
    float bv = b1[c];
    float acc0 = bv, acc1 = bv, acc2 = bv, acc3 = bv;
    for (int k = 0; k < D; k++) {
        float w = W1[k * DFF + c];
        acc0 = fmaf(as[0][k], w, acc0);
        acc1 = fmaf(as[1][k], w, acc1);
        acc2 = fmaf(as[2][k], w, acc2);
        acc3 = fmaf(as[3][k], w, acc3);
    }
    f1[(r0 + 0) * DFF + c] = fmaxf(acc0, 0.f);
    f1[(r0 + 1) * DFF + c] = fmaxf(acc1, 0.f);
    f1[(r0 + 2) * DFF + c] = fmaxf(acc2, 0.f);
    f1[(r0 + 3) * DFF + c] = fmaxf(acc3, 0.f);
}

// ---------- K7: split-K partials of f1 @ ffnW2 (+ ffnb2 on split 0) ----------
// grid (128, 4): 4 rows x k-split; block 256
__global__ __launch_bounds__(256) void k_ffn2p(
    const float* __restrict__ f1, const float* __restrict__ W2, const float* __restrict__ b2,
    float* __restrict__ part)
{
    __shared__ float fs[4][256];
    int r0 = blockIdx.x * 4;
    int ks = blockIdx.y;
    int c = threadIdx.x;
    for (int idx = threadIdx.x; idx < 4 * 256; idx += 256)
        fs[idx >> 8][idx & 255] = f1[(r0 + (idx >> 8)) * DFF + ks * 256 + (idx & 255)];
    __syncthreads();
    float acc0 = 0, acc1 = 0, acc2 = 0, acc3 = 0;
    if (ks == 0) { float bv = b2[c]; acc0 = acc1 = acc2 = acc3 = bv; }
    const float* w = W2 + (size_t)ks * 256 * D + c;
    for (int k = 0; k < 256; k++) {
        float wv = w[(size_t)k * D];
        acc0 = fmaf(fs[0][k], wv, acc0);
        acc1 = fmaf(fs[1][k], wv, acc1);
        acc2 = fmaf(fs[2][k], wv, acc2);
        acc3 = fmaf(fs[3][k], wv, acc3);
    }
    part[((size_t)ks * R_TOT + r0 + 0) * D + c] = acc0;
    part[((size_t)ks * R_TOT + r0 + 1) * D + c] = acc1;
    part[((size_t)ks * R_TOT + r0 + 2) * D + c] = acc2;
    part[((size_t)ks * R_TOT + r0 + 3) * D + c] = acc3;
}

// ---------- K8: h' = LN2(RES*o1 + ALT*(sum partials)) ----------
// grid 256 (2 rows), block 256
__global__ __launch_bounds__(256) void k_ffn2_ln(
    const float* __restrict__ part, const float* __restrict__ o1,
    const float* __restrict__ lng, const float* __restrict__ lnb,
    float* __restrict__ hout)
{
    __shared__ float red[256];
    int r0 = blockIdx.x * 2;
    int c = threadIdx.x;
    float gg = lng[c], bb = lnb[c];
#pragma unroll
    for (int row = 0; row < 2; row++) {
        int r = r0 + row;
        float f = part[((size_t)0 * R_TOT + r) * D + c]
                + part[((size_t)1 * R_TOT + r) * D + c]
                + part[((size_t)2 * R_TOT + r) * D + c]
                + part[((size_t)3 * R_TOT + r) * D + c];
        float v = RES * o1[r * D + c] + ALT * f;
        float mu = block_sum(v, red) * (1.0f / 256.0f);
        float dv = v - mu;
        float var = block_sum(dv * dv, red) * (1.0f / 256.0f);
        hout[r * D + c] = dv * rsqrtf(var + 1e-6f) * gg + bb;
    }
}

extern "C" void kernel_launch(void* const* d_in, const int* in_sizes, int n_in,
                              void* d_out, int out_size, void* d_ws, size_t ws_size,
                              hipStream_t stream)
{
    const int*   x       = (const int*)d_in[0];
    const float* mask    = (const float*)d_in[1];
    const int*   use_pos = (const int*)d_in[3];
    const float* pos_enc = (const float*)d_in[4];
    const float* emb_W   = (const float*)d_in[5];
    const float* emb_b   = (const float*)d_in[6];
    const float* nn_W1   = (const float*)d_in[7];
    const float* nn_b1   = (const float*)d_in[8];
    const float* nn_W2   = (const float*)d_in[9];
    const float* nn_b2   = (const float*)d_in[10];
    const float* w_W     = (const float*)d_in[11];
    const float* w_b     = (const float*)d_in[12];
    const float* out_W   = (const float*)d_in[13];
    const float* out_b   = (const float*)d_in[14];
    const float* ffn_W1  = (const float*)d_in[15];
    const float* ffn_b1  = (const float*)d_in[16];
    const float* ffn_W2  = (const float*)d_in[17];
    const float* ffn_b2  = (const float*)d_in[18];
    const float* ln1_g   = (const float*)d_in[19];
    const float* ln1_b   = (const float*)d_in[20];
    const float* ln2_g   = (const float*)d_in[21];
    const float* ln2_b   = (const float*)d_in[22];

    float* ws   = (float*)d_ws;
    float* h    = ws;                 // 131072
    float* qkv  = ws + 131072;        // 131072
    float* qa   = ws + 262144;        // 131072
    float* qb   = ws + 393216;        // 131072
    float* g    = ws + 524288;        // 131072 (NB*S*S)
    float* ao   = ws + 655360;        // 131072
    float* o1   = ws + 786432;        // 131072
    float* f1   = ws + 917504;        // 524288
    float* part = ws + 1441792;       // 524288

    k_embed<<<512, 256, 0, stream>>>(x, mask, use_pos, pos_enc, emb_W, emb_b, h);

    for (int l = 0; l < 2; l++) {
        k_qkv<<<128, 512, 0, stream>>>(h, w_W + l * D * D, w_b + l * D,
                                       nn_W1, nn_b1, qkv, qa, qb);
        k_g<<<128, 512, 0, stream>>>(qa, qb, nn_W2, g);
        k_attn<<<256, 256, 0, stream>>>(g, mask, nn_b2, qkv, ao);
        k_proj_ln<<<256, 256, 0, stream>>>(ao, out_W + l * D * D, out_b + l * D,
                                           h, ln1_g + l * D, ln1_b + l * D, o1);
        k_ffn1<<<dim3(128, 4), 256, 0, stream>>>(o1, ffn_W1 + l * D * DFF,
                                                 ffn_b1 + l * DFF, f1);
        k_ffn2p<<<dim3(128, 4), 256, 0, stream>>>(f1, ffn_W2 + l * DFF * D,
                                                  ffn_b2 + l * D, part);
        float* hout = (l == 1) ? (float*)d_out : h;
        k_ffn2_ln<<<256, 256, 0, stream>>>(part, o1, ln2_g + l * D, ln2_b + l * D, hout);
    }
}